// Round 3
// baseline (212.241 us; speedup 1.0000x reference)
//
#include <hip/hip_runtime.h>

#define BATCH  8192
#define NFEAT  2048
#define NFIELD 8
#define NFACT  64
#define FDIM   256
#define NPAIR  36

typedef short short8v __attribute__((ext_vector_type(8)));
typedef __bf16 bf16x8 __attribute__((ext_vector_type(8)));
typedef float f32x4 __attribute__((ext_vector_type(4)));

__device__ inline unsigned short f2bf(float f) {
    unsigned int u = __float_as_uint(f);
    unsigned int r = u + 0x7FFF + ((u >> 16) & 1);   // RNE
    return (unsigned short)(r >> 16);
}
__device__ inline float bf2f(unsigned short h) {
    return __uint_as_float(((unsigned int)h) << 16);
}
__device__ inline f32x4 mfma16(bf16x8 a, bf16x8 b, f32x4 c) {
    return __builtin_amdgcn_mfma_f32_16x16x32_bf16(a, b, c, 0, 0, 0);
}

// ---------------------------------------------------------------------------
// sv[i] = ||V[i, f2f[i], :]||^2
// ---------------------------------------------------------------------------
__global__ void sv_kernel(const float* __restrict__ V, const int* __restrict__ f2f,
                          float* __restrict__ sv) {
    int i = blockIdx.x * blockDim.x + threadIdx.x;
    if (i >= NFEAT) return;
    int f = f2f[i];
    const float* vp = V + (size_t)i * (NFIELD * NFACT) + (size_t)f * NFACT;
    float s = 0.f;
#pragma unroll
    for (int l = 0; l < NFACT; l += 4) {
        float4 v = *reinterpret_cast<const float4*>(vp + l);
        s += v.x * v.x + v.y * v.y + v.z * v.z + v.w * v.w;
    }
    sv[i] = s;
}

// ---------------------------------------------------------------------------
// Convert V -> bf16 hi/lo, fragment-linear layout (same layout as round 2):
//   off = ((((s*8+t)*8 + kc)*4 + ct)*64 + lane)*8
//   element = V[i = s*256 + kc*32 + (lane>>4)*8 + e][t][l = ct*16 + (lane&15)]
// ---------------------------------------------------------------------------
__global__ void convert_v(const float* __restrict__ V,
                          unsigned short* __restrict__ vh, unsigned short* __restrict__ vl) {
    const int tid = blockIdx.x * 256 + threadIdx.x;        // 0 .. 131071
    const int lane = tid & 63;
    const int ct = (tid >> 6) & 3;
    const int kc = (tid >> 8) & 7;
    const int t  = (tid >> 11) & 7;
    const int s  = tid >> 14;
    const int l  = ct * 16 + (lane & 15);
    const int i0 = s * 256 + kc * 32 + (lane >> 4) * 8;
    short8v hv, lv;
#pragma unroll
    for (int e = 0; e < 8; ++e) {
        float v = V[(size_t)(i0 + e) * (NFIELD * NFACT) + t * NFACT + l];
        unsigned short h = f2bf(v);
        hv[e] = (short)h;
        lv[e] = (short)f2bf(v - bf2f(h));
    }
    *reinterpret_cast<short8v*>(vh + (size_t)tid * 8) = hv;
    *reinterpret_cast<short8v*>(vl + (size_t)tid * 8) = lv;
}

// ---------------------------------------------------------------------------
// convert_x v2: coalesced x reads -> LDS tile -> fragment-linear writes.
// Block = 16 batch rows (one (rb, rt)); 256 threads; loop over 8 fields.
// Also computes out[row] = b0 + x.w - 0.25*sum(x^2*sv) directly (each row
// owned by exactly one wave -> plain store, no init kernel needed).
// X layout (round-2 compatible):
//   off = ((((rb*8 + s)*8 + kc)*8 + rt)*64 + lane)*8
//   element = x[row = rb*128 + rt*16 + (lane&15)][s*256 + kc*32 + (lane>>4)*8 + e]
// ---------------------------------------------------------------------------
__global__ __launch_bounds__(256) void convert_x2(
    const float* __restrict__ x, const float* __restrict__ w,
    const float* __restrict__ sv, const float* __restrict__ bptr,
    unsigned short* __restrict__ xh, unsigned short* __restrict__ xl,
    float* __restrict__ out) {
    __shared__ float tile[16][268];   // 268 % 32 = 12 -> worst 2-way alias (free)

    const int blk  = blockIdx.x;      // 0..511
    const int rb   = blk >> 3;
    const int rt   = blk & 7;
    const int row0 = blk * 16;
    const int tid  = threadIdx.x;
    const int lane = tid & 63;
    const int wv   = tid >> 6;        // wave id 0..3

    float lin[4] = {0.f, 0.f, 0.f, 0.f};
    float qq[4]  = {0.f, 0.f, 0.f, 0.f};

    for (int s = 0; s < 8; ++s) {
        const int col = s * 256 + lane * 4;
        float4 w4  = *reinterpret_cast<const float4*>(w + col);
        float4 sv4 = *reinterpret_cast<const float4*>(sv + col);
        __syncthreads();              // previous phase-B readers done
#pragma unroll
        for (int p = 0; p < 4; ++p) {
            int r = p * 4 + wv;       // wave wv handles rows {wv, wv+4, wv+8, wv+12}
            float4 v = *reinterpret_cast<const float4*>(
                x + (size_t)(row0 + r) * NFEAT + col);
            *reinterpret_cast<float4*>(&tile[r][lane * 4]) = v;
            lin[p] += v.x * w4.x + v.y * w4.y + v.z * w4.z + v.w * w4.w;
            qq[p]  += v.x * v.x * sv4.x + v.y * v.y * sv4.y
                    + v.z * v.z * sv4.z + v.w * v.w * sv4.w;
        }
        __syncthreads();              // tile staged
#pragma unroll
        for (int half = 0; half < 2; ++half) {
            const int kc = half * 4 + wv;          // wave-uniform kc
            const int r  = lane & 15;
            const int k0 = kc * 32 + (lane >> 4) * 8;
            float4 a = *reinterpret_cast<const float4*>(&tile[r][k0]);
            float4 b = *reinterpret_cast<const float4*>(&tile[r][k0 + 4]);
            float vs[8] = {a.x, a.y, a.z, a.w, b.x, b.y, b.z, b.w};
            short8v hv, lv;
#pragma unroll
            for (int e = 0; e < 8; ++e) {
                unsigned short h = f2bf(vs[e]);
                hv[e] = (short)h;
                lv[e] = (short)f2bf(vs[e] - bf2f(h));
            }
            size_t off = ((((size_t)(rb * 8 + s) * 8 + kc) * 8 + rt) * 64 + lane) * 8;
            *reinterpret_cast<short8v*>(xh + off) = hv;
            *reinterpret_cast<short8v*>(xl + off) = lv;
        }
    }

    // reduce lin/qq across the 64 lanes of each wave
#pragma unroll
    for (int off = 1; off < 64; off <<= 1) {
#pragma unroll
        for (int p = 0; p < 4; ++p) {
            lin[p] += __shfl_xor(lin[p], off, 64);
            qq[p]  += __shfl_xor(qq[p], off, 64);
        }
    }
    if (lane == 0) {
        float b0 = bptr[0];
#pragma unroll
        for (int p = 0; p < 4; ++p)
            out[row0 + p * 4 + wv] = b0 + lin[p] - 0.25f * qq[p];
    }
}

// ---------------------------------------------------------------------------
// pair_mfma v2: NO LDS, no barriers. Fragments read directly from global
// (fragment-linear -> each wave reads coalesced 1KB lines; V lines are shared
// by the block's 4 waves via L1). 3-way bf16 split: hh + hl + lh.
// Grid: 2304 linear blocks, pair-major XCD swizzle (2304 = 8 * 288) so all 64
// tile-blocks of a pair stay on one XCD (V slice stays L2-hot).
// ---------------------------------------------------------------------------
__global__ __launch_bounds__(256) void pair_mfma2(
    const unsigned short* __restrict__ xh, const unsigned short* __restrict__ xl,
    const unsigned short* __restrict__ vh, const unsigned short* __restrict__ vl,
    float* __restrict__ out) {
    const int id  = blockIdx.x;                 // 0..2303, dispatched round-robin
    const int swz = (id & 7) * 288 + (id >> 3); // XCD (id&7) owns contiguous 288
    const int pairIdx = swz >> 6;               // 0..35 (pair-major)
    const int tile    = swz & 63;

    int p = pairIdx, s = 0;
    while (p >= NFIELD - s) { p -= NFIELD - s; ++s; }
    const int t = s + p;
    const bool diag = (s == t);

    const int tid = threadIdx.x, lane = tid & 63, wid = tid >> 6;
    const int rt0 = wid * 2, rt1 = rt0 + 1;

    f32x4 accA[2][4] = {};
    f32x4 accB[2][4] = {};

    const size_t laneOff = (size_t)lane * 8;
    const size_t xbS = ((size_t)(tile * 8 + s) * 8) * 4096 + laneOff;
    const size_t xbT = ((size_t)(tile * 8 + t) * 8) * 4096 + laneOff;
    const size_t vbA = ((size_t)(s * 8 + t) * 8) * 2048 + laneOff;
    const size_t vbB = ((size_t)(t * 8 + s) * 8) * 2048 + laneOff;

    for (int kc = 0; kc < 8; ++kc) {
        const size_t xo = (size_t)kc * 4096;
        const size_t vo = (size_t)kc * 2048;

        bf16x8 ah0 = *reinterpret_cast<const bf16x8*>(xh + xbS + xo + rt0 * 512);
        bf16x8 ah1 = *reinterpret_cast<const bf16x8*>(xh + xbS + xo + rt1 * 512);
        bf16x8 al0 = *reinterpret_cast<const bf16x8*>(xl + xbS + xo + rt0 * 512);
        bf16x8 al1 = *reinterpret_cast<const bf16x8*>(xl + xbS + xo + rt1 * 512);
        bf16x8 vah[4], val[4];
#pragma unroll
        for (int ct = 0; ct < 4; ++ct) {
            vah[ct] = *reinterpret_cast<const bf16x8*>(vh + vbA + vo + ct * 512);
            val[ct] = *reinterpret_cast<const bf16x8*>(vl + vbA + vo + ct * 512);
        }
#pragma unroll
        for (int ct = 0; ct < 4; ++ct) {
            accA[0][ct] = mfma16(ah0, vah[ct], accA[0][ct]);
            accA[0][ct] = mfma16(ah0, val[ct], accA[0][ct]);
            accA[0][ct] = mfma16(al0, vah[ct], accA[0][ct]);
            accA[1][ct] = mfma16(ah1, vah[ct], accA[1][ct]);
            accA[1][ct] = mfma16(ah1, val[ct], accA[1][ct]);
            accA[1][ct] = mfma16(al1, vah[ct], accA[1][ct]);
        }
        if (!diag) {
            bf16x8 ch0 = *reinterpret_cast<const bf16x8*>(xh + xbT + xo + rt0 * 512);
            bf16x8 ch1 = *reinterpret_cast<const bf16x8*>(xh + xbT + xo + rt1 * 512);
            bf16x8 cl0 = *reinterpret_cast<const bf16x8*>(xl + xbT + xo + rt0 * 512);
            bf16x8 cl1 = *reinterpret_cast<const bf16x8*>(xl + xbT + xo + rt1 * 512);
            bf16x8 vbh[4], vbl[4];
#pragma unroll
            for (int ct = 0; ct < 4; ++ct) {
                vbh[ct] = *reinterpret_cast<const bf16x8*>(vh + vbB + vo + ct * 512);
                vbl[ct] = *reinterpret_cast<const bf16x8*>(vl + vbB + vo + ct * 512);
            }
#pragma unroll
            for (int ct = 0; ct < 4; ++ct) {
                accB[0][ct] = mfma16(ch0, vbh[ct], accB[0][ct]);
                accB[0][ct] = mfma16(ch0, vbl[ct], accB[0][ct]);
                accB[0][ct] = mfma16(cl0, vbh[ct], accB[0][ct]);
                accB[1][ct] = mfma16(ch1, vbh[ct], accB[1][ct]);
                accB[1][ct] = mfma16(ch1, vbl[ct], accB[1][ct]);
                accB[1][ct] = mfma16(cl1, vbh[ct], accB[1][ct]);
            }
        }
    }

    // epilogue: per-row dot over l (C layout: col(l)=lane&15, row=(lane>>4)*4+r)
    const float scale = diag ? 0.25f : 0.5f;
#pragma unroll
    for (int rti = 0; rti < 2; ++rti) {
#pragma unroll
        for (int r = 0; r < 4; ++r) {
            float v = 0.f;
#pragma unroll
            for (int ct = 0; ct < 4; ++ct)
                v += accA[rti][ct][r] * (diag ? accA[rti][ct][r] : accB[rti][ct][r]);
            v += __shfl_xor(v, 1, 64);
            v += __shfl_xor(v, 2, 64);
            v += __shfl_xor(v, 4, 64);
            v += __shfl_xor(v, 8, 64);
            if ((lane & 15) == 0) {
                int row = tile * 128 + (wid * 2 + rti) * 16 + (lane >> 4) * 4 + r;
                atomicAdd(&out[row], scale * v);
            }
        }
    }
}

// ===========================================================================
// Fallback fp32 path (round-1 kernels), used when ws_size is too small.
// ===========================================================================
#define BM 64
#define KC 64
#define XPAD 4

__global__ void base_kernel(const float* __restrict__ x, const float* __restrict__ bptr,
                            const float* __restrict__ w, const float* __restrict__ sv,
                            float* __restrict__ out) {
    const int row = blockIdx.x;
    const int tid = threadIdx.x;
    const float* xr = x + (size_t)row * NFEAT;
    float lin = 0.f, q = 0.f;
#pragma unroll
    for (int j = 0; j < 2; ++j) {
        int idx = j * 1024 + tid * 4;
        float4 xv = *reinterpret_cast<const float4*>(xr + idx);
        float4 wv = *reinterpret_cast<const float4*>(w + idx);
        float4 sq = *reinterpret_cast<const float4*>(sv + idx);
        lin += xv.x * wv.x + xv.y * wv.y + xv.z * wv.z + xv.w * wv.w;
        q   += xv.x * xv.x * sq.x + xv.y * xv.y * sq.y
             + xv.z * xv.z * sq.z + xv.w * xv.w * sq.w;
    }
#pragma unroll
    for (int off = 32; off >= 1; off >>= 1) {
        lin += __shfl_down(lin, off, 64);
        q   += __shfl_down(q, off, 64);
    }
    __shared__ float slin[4], sq4[4];
    const int wave = tid >> 6;
    if ((tid & 63) == 0) { slin[wave] = lin; sq4[wave] = q; }
    __syncthreads();
    if (tid == 0) {
        float L = slin[0] + slin[1] + slin[2] + slin[3];
        float Q = sq4[0] + sq4[1] + sq4[2] + sq4[3];
        out[row] = bptr[0] + L - 0.25f * Q;
    }
}

__global__ __launch_bounds__(256) void pair_kernel(const float* __restrict__ x,
                                                   const float* __restrict__ V,
                                                   float* __restrict__ out) {
    __shared__ float Xs[BM][KC + XPAD];
    __shared__ float Xt[BM][KC + XPAD];
    __shared__ float Vs[KC][NFACT];
    __shared__ float Vt[KC][NFACT];

    const int tile = blockIdx.x;
    int p = blockIdx.y;
    int s = 0;
    while (p >= NFIELD - s) { p -= NFIELD - s; ++s; }
    const int t = s + p;
    const bool diag = (s == t);

    const int tid  = threadIdx.x;
    const int lgrp = tid & 15;
    const int rgrp = tid >> 4;
    const int l0 = lgrp * 4;
    const int r0 = rgrp * 4;
    const int rowBase = tile * BM;

    float accA[4][4] = {};
    float accB[4][4] = {};

    for (int kc = 0; kc < FDIM; kc += KC) {
        __syncthreads();
#pragma unroll
        for (int it = 0; it < 4; ++it) {
            int rr = (tid >> 4) + it * 16;
            const float* gx = x + (size_t)(rowBase + rr) * NFEAT + s * FDIM + kc + (tid & 15) * 4;
            *reinterpret_cast<float4*>(&Xs[rr][(tid & 15) * 4]) =
                *reinterpret_cast<const float4*>(gx);
            if (!diag) {
                const float* gx2 = x + (size_t)(rowBase + rr) * NFEAT + t * FDIM + kc + (tid & 15) * 4;
                *reinterpret_cast<float4*>(&Xt[rr][(tid & 15) * 4]) =
                    *reinterpret_cast<const float4*>(gx2);
            }
        }
#pragma unroll
        for (int it = 0; it < 4; ++it) {
            int kk = (tid >> 4) + it * 16;
            const float* gv = V + (size_t)(s * FDIM + kc + kk) * (NFIELD * NFACT) + t * NFACT + (tid & 15) * 4;
            *reinterpret_cast<float4*>(&Vs[kk][(tid & 15) * 4]) =
                *reinterpret_cast<const float4*>(gv);
            if (!diag) {
                const float* gv2 = V + (size_t)(t * FDIM + kc + kk) * (NFIELD * NFACT) + s * NFACT + (tid & 15) * 4;
                *reinterpret_cast<float4*>(&Vt[kk][(tid & 15) * 4]) =
                    *reinterpret_cast<const float4*>(gv2);
            }
        }
        __syncthreads();

        for (int k = 0; k < KC; k += 4) {
            float xa[4][4], va[4][4];
#pragma unroll
            for (int r = 0; r < 4; ++r) {
                float4 v = *reinterpret_cast<const float4*>(&Xs[r0 + r][k]);
                xa[r][0] = v.x; xa[r][1] = v.y; xa[r][2] = v.z; xa[r][3] = v.w;
            }
#pragma unroll
            for (int kk = 0; kk < 4; ++kk) {
                float4 v = *reinterpret_cast<const float4*>(&Vs[k + kk][l0]);
                va[kk][0] = v.x; va[kk][1] = v.y; va[kk][2] = v.z; va[kk][3] = v.w;
            }
#pragma unroll
            for (int kk = 0; kk < 4; ++kk)
#pragma unroll
                for (int r = 0; r < 4; ++r)
#pragma unroll
                    for (int c = 0; c < 4; ++c)
                        accA[r][c] = fmaf(xa[r][kk], va[kk][c], accA[r][c]);

            if (!diag) {
                float xb[4][4], vb[4][4];
#pragma unroll
                for (int r = 0; r < 4; ++r) {
                    float4 v = *reinterpret_cast<const float4*>(&Xt[r0 + r][k]);
                    xb[r][0] = v.x; xb[r][1] = v.y; xb[r][2] = v.z; xb[r][3] = v.w;
                }
#pragma unroll
                for (int kk = 0; kk < 4; ++kk) {
                    float4 v = *reinterpret_cast<const float4*>(&Vt[k + kk][l0]);
                    vb[kk][0] = v.x; vb[kk][1] = v.y; vb[kk][2] = v.z; vb[kk][3] = v.w;
                }
#pragma unroll
                for (int kk = 0; kk < 4; ++kk)
#pragma unroll
                    for (int r = 0; r < 4; ++r)
#pragma unroll
                        for (int c = 0; c < 4; ++c)
                            accB[r][c] = fmaf(xb[r][kk], vb[kk][c], accB[r][c]);
            }
        }
    }

    float pr[4];
#pragma unroll
    for (int r = 0; r < 4; ++r) {
        float d = 0.f;
#pragma unroll
        for (int c = 0; c < 4; ++c)
            d += accA[r][c] * (diag ? accA[r][c] : accB[r][c]);
        pr[r] = d;
    }
#pragma unroll
    for (int off = 1; off < 16; off <<= 1) {
#pragma unroll
        for (int r = 0; r < 4; ++r)
            pr[r] += __shfl_xor(pr[r], off, 64);
    }
    if (lgrp == 0) {
        const float scale = diag ? 0.25f : 0.5f;
#pragma unroll
        for (int r = 0; r < 4; ++r)
            atomicAdd(&out[rowBase + r0 + r], scale * pr[r]);
    }
}

// ---------------------------------------------------------------------------
extern "C" void kernel_launch(void* const* d_in, const int* in_sizes, int n_in,
                              void* d_out, int out_size, void* d_ws, size_t ws_size,
                              hipStream_t stream) {
    const float* x   = (const float*)d_in[0];
    const float* b   = (const float*)d_in[1];
    const float* w   = (const float*)d_in[2];
    const float* V   = (const float*)d_in[3];
    const int*   f2f = (const int*)d_in[4];
    float* out = (float*)d_out;

    const size_t SZ_XH = 33554432;   // 8192*2048*2 B
    const size_t SZ_VH = 2097152;    // 2048*512*2 B
    const size_t NEED  = 2 * SZ_XH + 2 * SZ_VH + NFEAT * sizeof(float);

    if (ws_size >= NEED) {
        char* ws = (char*)d_ws;
        unsigned short* xhp = (unsigned short*)ws;
        unsigned short* xlp = (unsigned short*)(ws + SZ_XH);
        unsigned short* vhp = (unsigned short*)(ws + 2 * SZ_XH);
        unsigned short* vlp = (unsigned short*)(ws + 2 * SZ_XH + SZ_VH);
        float* sv = (float*)(ws + 2 * SZ_XH + 2 * SZ_VH);

        sv_kernel<<<(NFEAT + 255) / 256, 256, 0, stream>>>(V, f2f, sv);
        convert_v<<<131072 / 256, 256, 0, stream>>>(V, vhp, vlp);
        convert_x2<<<BATCH / 16, 256, 0, stream>>>(x, w, sv, b, xhp, xlp, out);
        pair_mfma2<<<64 * NPAIR, 256, 0, stream>>>(xhp, xlp, vhp, vlp, out);
    } else {
        float* sv = (float*)d_ws;
        sv_kernel<<<(NFEAT + 255) / 256, 256, 0, stream>>>(V, f2f, sv);
        base_kernel<<<BATCH, 256, 0, stream>>>(x, b, w, sv, out);
        dim3 grid(BATCH / BM, NPAIR);
        pair_kernel<<<grid, 256, 0, stream>>>(x, V, out);
    }
}

// Round 4
// 178.907 us; speedup vs baseline: 1.1863x; 1.1863x over previous
//
#include <hip/hip_runtime.h>

#define BATCH  8192
#define NFEAT  2048
#define NFIELD 8
#define NFACT  64
#define FDIM   256
#define NPAIR  36

typedef short short8v __attribute__((ext_vector_type(8)));
typedef __bf16 bf16x8 __attribute__((ext_vector_type(8)));
typedef float f32x4 __attribute__((ext_vector_type(4)));

__device__ inline unsigned short f2bf(float f) {
    unsigned int u = __float_as_uint(f);
    unsigned int r = u + 0x7FFF + ((u >> 16) & 1);   // RNE
    return (unsigned short)(r >> 16);
}
__device__ inline float bf2f(unsigned short h) {
    return __uint_as_float(((unsigned int)h) << 16);
}
__device__ inline f32x4 mfma16(bf16x8 a, bf16x8 b, f32x4 c) {
    return __builtin_amdgcn_mfma_f32_16x16x32_bf16(a, b, c, 0, 0, 0);
}

// ---------------------------------------------------------------------------
// sv[i] = ||V[i, f2f[i], :]||^2
// ---------------------------------------------------------------------------
__global__ void sv_kernel(const float* __restrict__ V, const int* __restrict__ f2f,
                          float* __restrict__ sv) {
    int i = blockIdx.x * blockDim.x + threadIdx.x;
    if (i >= NFEAT) return;
    int f = f2f[i];
    const float* vp = V + (size_t)i * (NFIELD * NFACT) + (size_t)f * NFACT;
    float s = 0.f;
#pragma unroll
    for (int l = 0; l < NFACT; l += 4) {
        float4 v = *reinterpret_cast<const float4*>(vp + l);
        s += v.x * v.x + v.y * v.y + v.z * v.z + v.w * v.w;
    }
    sv[i] = s;
}

// ---------------------------------------------------------------------------
// out[i] = b[0]  (d_out is poisoned before every call; convert_x3 and the
// pair kernel atomically accumulate on top)
// ---------------------------------------------------------------------------
__global__ void init_out(const float* __restrict__ bptr, float* __restrict__ out) {
    int i = blockIdx.x * blockDim.x + threadIdx.x;
    if (i < BATCH) out[i] = bptr[0];
}

// ---------------------------------------------------------------------------
// Convert V -> bf16 hi/lo, fragment-linear layout:
//   off = ((((s*8+t)*8 + kc)*4 + ct)*64 + lane)*8
//   element = V[i = s*256 + kc*32 + (lane>>4)*8 + e][t][l = ct*16 + (lane&15)]
// ---------------------------------------------------------------------------
__global__ void convert_v(const float* __restrict__ V,
                          unsigned short* __restrict__ vh, unsigned short* __restrict__ vl) {
    const int tid = blockIdx.x * 256 + threadIdx.x;        // 0 .. 131071
    const int lane = tid & 63;
    const int ct = (tid >> 6) & 3;
    const int kc = (tid >> 8) & 7;
    const int t  = (tid >> 11) & 7;
    const int s  = tid >> 14;
    const int l  = ct * 16 + (lane & 15);
    const int i0 = s * 256 + kc * 32 + (lane >> 4) * 8;
    short8v hv, lv;
#pragma unroll
    for (int e = 0; e < 8; ++e) {
        float v = V[(size_t)(i0 + e) * (NFIELD * NFACT) + t * NFACT + l];
        unsigned short h = f2bf(v);
        hv[e] = (short)h;
        lv[e] = (short)f2bf(v - bf2f(h));
    }
    *reinterpret_cast<short8v*>(vh + (size_t)tid * 8) = hv;
    *reinterpret_cast<short8v*>(vl + (size_t)tid * 8) = lv;
}

// ---------------------------------------------------------------------------
// convert_x3: one block per (16-row tile, field). 4096 blocks, 256 threads,
// ONE barrier. Coalesced 1KB reads -> LDS -> coalesced 1KB fragment writes.
// Fuses the linear + self-quadratic terms: atomicAdd per (row, field).
// X layout (identical to r2/r3):
//   off = ((((rb*8 + s)*8 + kc)*8 + rt)*64 + lane)*8
//   element = x[rb*128 + rt*16 + (lane&15)][s*256 + kc*32 + (lane>>4)*8 + e]
// ---------------------------------------------------------------------------
__global__ __launch_bounds__(256) void convert_x3(
    const float* __restrict__ x, const float* __restrict__ w,
    const float* __restrict__ sv,
    unsigned short* __restrict__ xh, unsigned short* __restrict__ xl,
    float* __restrict__ out) {
    __shared__ float tile[16][260];     // pad 4: write/read patterns ~conflict-free

    const int bid = blockIdx.x;         // 0..4095
    const int rb  = bid >> 6;           // 0..63
    const int rt  = (bid >> 3) & 7;     // 0..7
    const int s   = bid & 7;            // 0..7
    const int row0 = rb * 128 + rt * 16;

    const int tid  = threadIdx.x;
    const int lane = tid & 63;
    const int wv   = tid >> 6;          // 0..3

    // per-lane w/sv slice for this field (same cols for every row)
    const int col = s * 256 + lane * 4;
    float4 w4  = *reinterpret_cast<const float4*>(w + col);
    float4 sv4 = *reinterpret_cast<const float4*>(sv + col);

    float lq[4];
#pragma unroll
    for (int p = 0; p < 4; ++p) {
        const int r = wv * 4 + p;       // wave wv owns rows wv*4 .. wv*4+3
        float4 v = *reinterpret_cast<const float4*>(
            x + (size_t)(row0 + r) * NFEAT + col);
        *reinterpret_cast<float4*>(&tile[r][lane * 4]) = v;
        float lin = v.x * w4.x + v.y * w4.y + v.z * w4.z + v.w * w4.w;
        float q   = v.x * v.x * sv4.x + v.y * v.y * sv4.y
                  + v.z * v.z * sv4.z + v.w * v.w * sv4.w;
        lq[p] = lin - 0.25f * q;
    }
    // reduce each row's partial across the wave's 64 lanes
#pragma unroll
    for (int off = 1; off < 64; off <<= 1)
#pragma unroll
        for (int p = 0; p < 4; ++p)
            lq[p] += __shfl_xor(lq[p], off, 64);
    if (lane == 0) {
#pragma unroll
        for (int p = 0; p < 4; ++p)
            atomicAdd(&out[row0 + wv * 4 + p], lq[p]);
    }

    __syncthreads();

    // fragment writes: wave wv handles kc = wv and wv+4
#pragma unroll
    for (int half = 0; half < 2; ++half) {
        const int kc = half * 4 + wv;
        const int r  = lane & 15;
        const int k0 = kc * 32 + (lane >> 4) * 8;
        float4 a = *reinterpret_cast<const float4*>(&tile[r][k0]);
        float4 b = *reinterpret_cast<const float4*>(&tile[r][k0 + 4]);
        float vs[8] = {a.x, a.y, a.z, a.w, b.x, b.y, b.z, b.w};
        short8v hv, lv;
#pragma unroll
        for (int e = 0; e < 8; ++e) {
            unsigned short h = f2bf(vs[e]);
            hv[e] = (short)h;
            lv[e] = (short)f2bf(vs[e] - bf2f(h));
        }
        size_t off = ((((size_t)(rb * 8 + s) * 8 + kc) * 8 + rt) * 64 + lane) * 8;
        *reinterpret_cast<short8v*>(xh + off) = hv;
        *reinterpret_cast<short8v*>(xl + off) = lv;
    }
}

// ---------------------------------------------------------------------------
// pair_mfma3: LDS-staged (r2 structure) + 2-phase prefetch + tile-major XCD
// swizzle. Wave roles for staging: wid0 xh(s)+vh(s,t); wid1 xl(s)+vl(s,t);
// wid2 xh(t)+vh(t,s); wid3 xl(t)+vl(t,s). 3-way bf16 split: hh + hl + lh.
// ---------------------------------------------------------------------------
__global__ __launch_bounds__(256, 3) void pair_mfma3(
    const unsigned short* __restrict__ xh, const unsigned short* __restrict__ xl,
    const unsigned short* __restrict__ vh, const unsigned short* __restrict__ vl,
    float* __restrict__ out) {
    __shared__ unsigned short lds[24576];   // 48 KB
    // X: 4096 elems each at 0 / 4096 / 8192 / 12288 (xh_s, xl_s, xh_t, xl_t)
    // V: 2048 elems each at 16384 / 18432 / 20480 / 22528 (vh_A, vl_A, vh_B, vl_B)

    // tile-major XCD swizzle: XCD (id&7) owns 8 consecutive row-tiles for all
    // 36 pairs -> per-XCD X working set 8 MB, V 4 MB (L2/L3-friendly).
    const int id    = blockIdx.x;            // 0..2303
    const int local = id >> 3;               // 0..287
    const int tile  = (id & 7) * 8 + local / 36;
    int p = local % 36;
    int s = 0;
    while (p >= NFIELD - s) { p -= NFIELD - s; ++s; }
    const int t = s + p;
    const bool diag = (s == t);

    const int tid = threadIdx.x, lane = tid & 63, wid = tid >> 6;
    const int rt0 = wid * 2, rt1 = rt0 + 1;

    f32x4 accA[2][4] = {};
    f32x4 accB[2][4] = {};

    const unsigned short* xsrc = (wid & 1) ? xl : xh;
    const unsigned short* vsrc = (wid & 1) ? vl : vh;
    const int f     = (wid < 2) ? s : t;
    const int vpair = (wid < 2) ? (s * 8 + t) : (t * 8 + s);
    const int xdst  = wid * 4096;
    const int vdst  = 16384 + wid * 2048;
    const bool active = !(diag && wid >= 2);

    const size_t xbase = ((size_t)(tile * 8 + f) * 8) * 4096 + (size_t)lane * 8;
    const size_t vbase = ((size_t)(vpair * 8)) * 2048 + (size_t)lane * 8;

    short8v xr[8], vr[4];
    if (active) {                       // prologue: chunk 0 -> regs
#pragma unroll
        for (int rt = 0; rt < 8; ++rt)
            xr[rt] = *reinterpret_cast<const short8v*>(xsrc + xbase + rt * 512);
#pragma unroll
        for (int ct = 0; ct < 4; ++ct)
            vr[ct] = *reinterpret_cast<const short8v*>(vsrc + vbase + ct * 512);
    }

    for (int kc = 0; kc < 8; ++kc) {
        __syncthreads();               // previous chunk's readers done
        if (active) {
#pragma unroll
            for (int rt = 0; rt < 8; ++rt)
                *reinterpret_cast<short8v*>(&lds[xdst + rt * 512 + lane * 8]) = xr[rt];
#pragma unroll
            for (int ct = 0; ct < 4; ++ct)
                *reinterpret_cast<short8v*>(&lds[vdst + ct * 512 + lane * 8]) = vr[ct];
        }
        __syncthreads();               // tile staged

        // issue next chunk's loads BEFORE compute: vmcnt-wait only hits at
        // next iteration's LDS write -> latency hides under the MFMA cluster
        if (kc < 7 && active) {
            const size_t xo = xbase + (size_t)(kc + 1) * 4096;
            const size_t vo = vbase + (size_t)(kc + 1) * 2048;
#pragma unroll
            for (int rt = 0; rt < 8; ++rt)
                xr[rt] = *reinterpret_cast<const short8v*>(xsrc + xo + rt * 512);
#pragma unroll
            for (int ct = 0; ct < 4; ++ct)
                vr[ct] = *reinterpret_cast<const short8v*>(vsrc + vo + ct * 512);
        }

        bf16x8 ah0 = *reinterpret_cast<const bf16x8*>(&lds[0     + rt0 * 512 + lane * 8]);
        bf16x8 ah1 = *reinterpret_cast<const bf16x8*>(&lds[0     + rt1 * 512 + lane * 8]);
        bf16x8 al0 = *reinterpret_cast<const bf16x8*>(&lds[4096  + rt0 * 512 + lane * 8]);
        bf16x8 al1 = *reinterpret_cast<const bf16x8*>(&lds[4096  + rt1 * 512 + lane * 8]);
#pragma unroll
        for (int ct = 0; ct < 4; ++ct) {
            bf16x8 bh = *reinterpret_cast<const bf16x8*>(&lds[16384 + ct * 512 + lane * 8]);
            bf16x8 bl = *reinterpret_cast<const bf16x8*>(&lds[18432 + ct * 512 + lane * 8]);
            accA[0][ct] = mfma16(ah0, bh, accA[0][ct]);
            accA[0][ct] = mfma16(ah0, bl, accA[0][ct]);
            accA[0][ct] = mfma16(al0, bh, accA[0][ct]);
            accA[1][ct] = mfma16(ah1, bh, accA[1][ct]);
            accA[1][ct] = mfma16(ah1, bl, accA[1][ct]);
            accA[1][ct] = mfma16(al1, bh, accA[1][ct]);
        }
        if (!diag) {
            bf16x8 ch0 = *reinterpret_cast<const bf16x8*>(&lds[8192  + rt0 * 512 + lane * 8]);
            bf16x8 ch1 = *reinterpret_cast<const bf16x8*>(&lds[8192  + rt1 * 512 + lane * 8]);
            bf16x8 cl0 = *reinterpret_cast<const bf16x8*>(&lds[12288 + rt0 * 512 + lane * 8]);
            bf16x8 cl1 = *reinterpret_cast<const bf16x8*>(&lds[12288 + rt1 * 512 + lane * 8]);
#pragma unroll
            for (int ct = 0; ct < 4; ++ct) {
                bf16x8 bh = *reinterpret_cast<const bf16x8*>(&lds[20480 + ct * 512 + lane * 8]);
                bf16x8 bl = *reinterpret_cast<const bf16x8*>(&lds[22528 + ct * 512 + lane * 8]);
                accB[0][ct] = mfma16(ch0, bh, accB[0][ct]);
                accB[0][ct] = mfma16(ch0, bl, accB[0][ct]);
                accB[0][ct] = mfma16(cl0, bh, accB[0][ct]);
                accB[1][ct] = mfma16(ch1, bh, accB[1][ct]);
                accB[1][ct] = mfma16(ch1, bl, accB[1][ct]);
                accB[1][ct] = mfma16(cl1, bh, accB[1][ct]);
            }
        }
    }

    // epilogue: per-row dot over l (C layout: col=lane&15, row=(lane>>4)*4+r)
    const float scale = diag ? 0.25f : 0.5f;
#pragma unroll
    for (int rti = 0; rti < 2; ++rti) {
#pragma unroll
        for (int r = 0; r < 4; ++r) {
            float v = 0.f;
#pragma unroll
            for (int ct = 0; ct < 4; ++ct)
                v += accA[rti][ct][r] * (diag ? accA[rti][ct][r] : accB[rti][ct][r]);
            v += __shfl_xor(v, 1, 64);
            v += __shfl_xor(v, 2, 64);
            v += __shfl_xor(v, 4, 64);
            v += __shfl_xor(v, 8, 64);
            if ((lane & 15) == 0) {
                int row = tile * 128 + (wid * 2 + rti) * 16 + (lane >> 4) * 4 + r;
                atomicAdd(&out[row], scale * v);
            }
        }
    }
}

// ===========================================================================
// Fallback fp32 path (round-1 kernels), used when ws_size is too small.
// ===========================================================================
#define BM 64
#define KC 64
#define XPAD 4

__global__ void base_kernel(const float* __restrict__ x, const float* __restrict__ bptr,
                            const float* __restrict__ w, const float* __restrict__ sv,
                            float* __restrict__ out) {
    const int row = blockIdx.x;
    const int tid = threadIdx.x;
    const float* xr = x + (size_t)row * NFEAT;
    float lin = 0.f, q = 0.f;
#pragma unroll
    for (int j = 0; j < 2; ++j) {
        int idx = j * 1024 + tid * 4;
        float4 xv = *reinterpret_cast<const float4*>(xr + idx);
        float4 wv = *reinterpret_cast<const float4*>(w + idx);
        float4 sq = *reinterpret_cast<const float4*>(sv + idx);
        lin += xv.x * wv.x + xv.y * wv.y + xv.z * wv.z + xv.w * wv.w;
        q   += xv.x * xv.x * sq.x + xv.y * xv.y * sq.y
             + xv.z * xv.z * sq.z + xv.w * xv.w * sq.w;
    }
#pragma unroll
    for (int off = 32; off >= 1; off >>= 1) {
        lin += __shfl_down(lin, off, 64);
        q   += __shfl_down(q, off, 64);
    }
    __shared__ float slin[4], sq4[4];
    const int wave = tid >> 6;
    if ((tid & 63) == 0) { slin[wave] = lin; sq4[wave] = q; }
    __syncthreads();
    if (tid == 0) {
        float L = slin[0] + slin[1] + slin[2] + slin[3];
        float Q = sq4[0] + sq4[1] + sq4[2] + sq4[3];
        out[row] = bptr[0] + L - 0.25f * Q;
    }
}

__global__ __launch_bounds__(256) void pair_kernel(const float* __restrict__ x,
                                                   const float* __restrict__ V,
                                                   float* __restrict__ out) {
    __shared__ float Xs[BM][KC + XPAD];
    __shared__ float Xt[BM][KC + XPAD];
    __shared__ float Vs[KC][NFACT];
    __shared__ float Vt[KC][NFACT];

    const int tile = blockIdx.x;
    int p = blockIdx.y;
    int s = 0;
    while (p >= NFIELD - s) { p -= NFIELD - s; ++s; }
    const int t = s + p;
    const bool diag = (s == t);

    const int tid  = threadIdx.x;
    const int lgrp = tid & 15;
    const int rgrp = tid >> 4;
    const int l0 = lgrp * 4;
    const int r0 = rgrp * 4;
    const int rowBase = tile * BM;

    float accA[4][4] = {};
    float accB[4][4] = {};

    for (int kc = 0; kc < FDIM; kc += KC) {
        __syncthreads();
#pragma unroll
        for (int it = 0; it < 4; ++it) {
            int rr = (tid >> 4) + it * 16;
            const float* gx = x + (size_t)(rowBase + rr) * NFEAT + s * FDIM + kc + (tid & 15) * 4;
            *reinterpret_cast<float4*>(&Xs[rr][(tid & 15) * 4]) =
                *reinterpret_cast<const float4*>(gx);
            if (!diag) {
                const float* gx2 = x + (size_t)(rowBase + rr) * NFEAT + t * FDIM + kc + (tid & 15) * 4;
                *reinterpret_cast<float4*>(&Xt[rr][(tid & 15) * 4]) =
                    *reinterpret_cast<const float4*>(gx2);
            }
        }
#pragma unroll
        for (int it = 0; it < 4; ++it) {
            int kk = (tid >> 4) + it * 16;
            const float* gv = V + (size_t)(s * FDIM + kc + kk) * (NFIELD * NFACT) + t * NFACT + (tid & 15) * 4;
            *reinterpret_cast<float4*>(&Vs[kk][(tid & 15) * 4]) =
                *reinterpret_cast<const float4*>(gv);
            if (!diag) {
                const float* gv2 = V + (size_t)(t * FDIM + kc + kk) * (NFIELD * NFACT) + s * NFACT + (tid & 15) * 4;
                *reinterpret_cast<float4*>(&Vt[kk][(tid & 15) * 4]) =
                    *reinterpret_cast<const float4*>(gv2);
            }
        }
        __syncthreads();

        for (int k = 0; k < KC; k += 4) {
            float xa[4][4], va[4][4];
#pragma unroll
            for (int r = 0; r < 4; ++r) {
                float4 v = *reinterpret_cast<const float4*>(&Xs[r0 + r][k]);
                xa[r][0] = v.x; xa[r][1] = v.y; xa[r][2] = v.z; xa[r][3] = v.w;
            }
#pragma unroll
            for (int kk = 0; kk < 4; ++kk) {
                float4 v = *reinterpret_cast<const float4*>(&Vs[k + kk][l0]);
                va[kk][0] = v.x; va[kk][1] = v.y; va[kk][2] = v.z; va[kk][3] = v.w;
            }
#pragma unroll
            for (int kk = 0; kk < 4; ++kk)
#pragma unroll
                for (int r = 0; r < 4; ++r)
#pragma unroll
                    for (int c = 0; c < 4; ++c)
                        accA[r][c] = fmaf(xa[r][kk], va[kk][c], accA[r][c]);

            if (!diag) {
                float xb[4][4], vb[4][4];
#pragma unroll
                for (int r = 0; r < 4; ++r) {
                    float4 v = *reinterpret_cast<const float4*>(&Xt[r0 + r][k]);
                    xb[r][0] = v.x; xb[r][1] = v.y; xb[r][2] = v.z; xb[r][3] = v.w;
                }
#pragma unroll
                for (int kk = 0; kk < 4; ++kk) {
                    float4 v = *reinterpret_cast<const float4*>(&Vt[k + kk][l0]);
                    vb[kk][0] = v.x; vb[kk][1] = v.y; vb[kk][2] = v.z; vb[kk][3] = v.w;
                }
#pragma unroll
                for (int kk = 0; kk < 4; ++kk)
#pragma unroll
                    for (int r = 0; r < 4; ++r)
#pragma unroll
                        for (int c = 0; c < 4; ++c)
                            accB[r][c] = fmaf(xb[r][kk], vb[kk][c], accB[r][c]);
            }
        }
    }

    float pr[4];
#pragma unroll
    for (int r = 0; r < 4; ++r) {
        float d = 0.f;
#pragma unroll
        for (int c = 0; c < 4; ++c)
            d += accA[r][c] * (diag ? accA[r][c] : accB[r][c]);
        pr[r] = d;
    }
#pragma unroll
    for (int off = 1; off < 16; off <<= 1) {
#pragma unroll
        for (int r = 0; r < 4; ++r)
            pr[r] += __shfl_xor(pr[r], off, 64);
    }
    if (lgrp == 0) {
        const float scale = diag ? 0.25f : 0.5f;
#pragma unroll
        for (int r = 0; r < 4; ++r)
            atomicAdd(&out[rowBase + r0 + r], scale * pr[r]);
    }
}

// ---------------------------------------------------------------------------
extern "C" void kernel_launch(void* const* d_in, const int* in_sizes, int n_in,
                              void* d_out, int out_size, void* d_ws, size_t ws_size,
                              hipStream_t stream) {
    const float* x   = (const float*)d_in[0];
    const float* b   = (const float*)d_in[1];
    const float* w   = (const float*)d_in[2];
    const float* V   = (const float*)d_in[3];
    const int*   f2f = (const int*)d_in[4];
    float* out = (float*)d_out;

    const size_t SZ_XH = 33554432;   // 8192*2048*2 B
    const size_t SZ_VH = 2097152;    // 2048*512*2 B
    const size_t NEED  = 2 * SZ_XH + 2 * SZ_VH + NFEAT * sizeof(float);

    if (ws_size >= NEED) {
        char* ws = (char*)d_ws;
        unsigned short* xhp = (unsigned short*)ws;
        unsigned short* xlp = (unsigned short*)(ws + SZ_XH);
        unsigned short* vhp = (unsigned short*)(ws + 2 * SZ_XH);
        unsigned short* vlp = (unsigned short*)(ws + 2 * SZ_XH + SZ_VH);
        float* sv = (float*)(ws + 2 * SZ_XH + 2 * SZ_VH);

        sv_kernel<<<(NFEAT + 255) / 256, 256, 0, stream>>>(V, f2f, sv);
        init_out<<<(BATCH + 255) / 256, 256, 0, stream>>>(b, out);
        convert_v<<<131072 / 256, 256, 0, stream>>>(V, vhp, vlp);
        convert_x3<<<4096, 256, 0, stream>>>(x, w, sv, xhp, xlp, out);
        pair_mfma3<<<64 * NPAIR, 256, 0, stream>>>(xhp, xlp, vhp, vlp, out);
    } else {
        float* sv = (float*)d_ws;
        sv_kernel<<<(NFEAT + 255) / 256, 256, 0, stream>>>(V, f2f, sv);
        base_kernel<<<BATCH, 256, 0, stream>>>(x, b, w, sv, out);
        dim3 grid(BATCH / BM, NPAIR);
        pair_kernel<<<grid, 256, 0, stream>>>(x, V, out);
    }
}